// Round 10
// baseline (12112.109 us; speedup 1.0000x reference)
//
#include <hip/hip_runtime.h>
#include <cstdint>
#include <cstddef>

#define T_SEQ 1024
#define BATCH 64
#define NH 2048
#define HSZ (BATCH * NH)          // halves per h rotation slot
// NINP == 2048 as well

typedef _Float16 half8 __attribute__((ext_vector_type(8)));
typedef _Float16 half4 __attribute__((ext_vector_type(4)));
typedef float f32x4 __attribute__((ext_vector_type(4)));
typedef unsigned u32x4 __attribute__((ext_vector_type(4)));

__device__ inline void gload_lds16(const void* g, void* l) {
    __builtin_amdgcn_global_load_lds(
        (const __attribute__((address_space(1))) uint32_t*)g,
        (__attribute__((address_space(3))) uint32_t*)l,
        16, 0, 0);
}

// ---- LLC-scope (sc0 sc1) ops: complete at the coherence point (MALL). -----
#define LLC_LD16NW(dst, addr)                                                \
    asm volatile("global_load_dwordx4 %0, %1, off sc0 sc1"                   \
                 : "=v"(dst) : "v"(addr))
#define LLC_ST2(addr, val)                                                   \
    asm volatile("global_store_short %0, %1, off sc0 sc1"                    \
                 :: "v"(addr), "v"(val) : "memory")
#define LLC_ST16(addr, val)                                                  \
    asm volatile("global_store_dwordx4 %0, %1, off sc0 sc1"                  \
                 :: "v"(addr), "v"(val) : "memory")

// Explicit drain: inline-asm VMEM ops are INVISIBLE to hipcc's waitcnt
// insertion (r5 lesson). Every asm-store -> publish ordering drains
// explicitly; every asm-load use is fenced with sched_barrier(0) (rule #18).
__device__ inline void wait_vm0() {
    asm volatile("s_waitcnt vmcnt(0)" ::: "memory");
}

#define CANARY32 0xFFFFFFFFu   // two fp16 NaNs; unproducible by the arithmetic
#define CANARY16 0xFFFFu

// All-halves canary test: 16B stores are only 64-bit single-copy atomic, so a
// concurrent reader may see a TORN slot (half data, half canary). Accept a
// slot only when EVERY half is non-canary (r9 bug: dword0-only check let a
// torn read feed NaN canaries into the reduction).
__device__ inline bool no_canary16(const u32x4& q) {
    bool ok = true;
#pragma unroll
    for (int d = 0; d < 4; ++d)
        ok = ok && ((q[d] & 0xFFFFu) != CANARY16) && ((q[d] >> 16) != CANARY16);
    return ok;
}

// ---------------- fp32 -> fp16 conversion (vectorized, n % 4 == 0) ----------
__global__ __launch_bounds__(256) void cvt_f32_f16(const float* __restrict__ src,
                                                   _Float16* __restrict__ dst,
                                                   long long n) {
    long long i = ((long long)blockIdx.x * 256 + threadIdx.x) * 4;
    long long stride = (long long)gridDim.x * 256 * 4;
    for (; i < n; i += stride) {
        const float4 v = *(const float4*)(src + i);
        half4 o;
        o[0] = (_Float16)v.x; o[1] = (_Float16)v.y;
        o[2] = (_Float16)v.z; o[3] = (_Float16)v.w;
        *(half4*)(dst + i) = o;
    }
}

// ---------------- projection GEMM: C[m][n] = sum_k A[m][k] * B[n][k] --------
// A: [M][2048] fp16, B: [6144][2048] fp16 (Wcx|Wix|Wfx rows), C: [M][6144] fp16
__global__ __launch_bounds__(256) void proj_gemm(const _Float16* __restrict__ A,
                                                 const _Float16* __restrict__ B,
                                                 _Float16* __restrict__ C, int M) {
    __shared__ _Float16 As[128][64];
    __shared__ _Float16 Bs[128][64];
    const int NBN = 48;                 // 6144 / 128
    const int nbm = M >> 7;
    const int nwg = nbm * NBN;          // divisible by 8 (M >= 2048)
    const int per = nwg >> 3;
    const int bid = blockIdx.x;
    const int swz = (bid & 7) * per + (bid >> 3);   // XCD-aware swizzle (bijective)
    const int bm = swz / NBN, bn = swz % NBN;

    const int tid = threadIdx.x;
    const int lane = tid & 63, w = tid >> 6;
    const int wm = w & 1, wn = w >> 1;

    f32x4 acc[4][4] = {};

    const int srow = lane >> 3;         // 0..7
    const int scol = (lane & 7) * 8;    // half units

    for (int bk = 0; bk < NH / 64; ++bk) {
#pragma unroll
        for (int i = 0; i < 4; ++i) {
            int r = w * 32 + i * 8;
            const _Float16* gA = A + (size_t)(bm * 128 + r + srow) * NH + bk * 64 + scol;
            gload_lds16(gA, &As[r][0]);
            const _Float16* gB = B + (size_t)(bn * 128 + r + srow) * NH + bk * 64 + scol;
            gload_lds16(gB, &Bs[r][0]);
        }
        __syncthreads();
#pragma unroll
        for (int kk = 0; kk < 2; ++kk) {
            half8 af[4], bf[4];
#pragma unroll
            for (int mi = 0; mi < 4; ++mi)
                af[mi] = *(const half8*)&As[wm * 64 + mi * 16 + (lane & 15)][kk * 32 + (lane >> 4) * 8];
#pragma unroll
            for (int ni = 0; ni < 4; ++ni)
                bf[ni] = *(const half8*)&Bs[wn * 64 + ni * 16 + (lane & 15)][kk * 32 + (lane >> 4) * 8];
#pragma unroll
            for (int mi = 0; mi < 4; ++mi)
#pragma unroll
                for (int ni = 0; ni < 4; ++ni)
                    acc[mi][ni] = __builtin_amdgcn_mfma_f32_16x16x32_f16(af[mi], bf[ni], acc[mi][ni], 0, 0, 0);
        }
        __syncthreads();
    }
#pragma unroll
    for (int mi = 0; mi < 4; ++mi)
#pragma unroll
        for (int ni = 0; ni < 4; ++ni)
#pragma unroll
            for (int r = 0; r < 4; ++r) {
                int m = bm * 128 + wm * 64 + mi * 16 + (lane >> 4) * 4 + r;
                int n = bn * 128 + wn * 64 + ni * 16 + (lane & 15);
                C[(size_t)m * 6144 + n] = (_Float16)acc[mi][ni][r];
            }
}

// ---------------- persistent scan kernel (all-canary, zero flags) -----------
// 256 WGs x 512 thr, 1 WG/CU. WG = (g of 32 b-rows, js of 64 cols, ks of 512 k)
// from blockIdx (r6-verified mapping). h lives in a DEPTH-4 rotating fp16
// buffer; values are self-certifying (canary 0xFFFF = fp16 NaN). Per step:
//  all:    poll own h[4 rows x 512 k] chunks against canary (poll IS the load)
//          -> LDS stage -> GEMM (32 MFMA/wave)
//  ks!=0:  ONE packed 16B fp16 partial store (data IS flag). Done.
//  ks==0:  poll 3 partial slots (ALL-halves canary check: 16B stores tear at
//          64-bit granularity), re-arm partial canaries + h slot (t+3)&3,
//          epilogue in VALU (hides re-arm drain), ONE vmcnt(0), h stores.
// Re-arm safety: owner(t)'s dependency cone covers ALL readers of input t-1
// (own staging poll proves owners 0..7 published h_t; partials from writers
// ks=1..3 prove owners 8..31 published; publication implies that owner and
// its writers finished staging t-1); slot (t+3)&3 is next written at t+2 by
// THIS SAME WG (program order + step-t+2 vmcnt(0) before publish).
__global__ __launch_bounds__(512, 1) void scan_kernel(
    const _Float16* __restrict__ proj,   // [nsteps*64][6144] fp16 (c | ix | fx)
    const _Float16* __restrict__ Wr,     // [2][2048][2048] fp16 (W_ih, W_fh)
    _Float16* hslab,                     // [4][64][2048] fp16 rotation
    const float* __restrict__ b_i, const float* __restrict__ b_f,
    float* __restrict__ out,             // d_out: [1024][64][2048] + [64][2048]
    _Float16* part, int t0, int nsteps) {
    extern __shared__ char smem[];
    _Float16* Wlds = (_Float16*)smem;          // 131072 B
    char* hstage = smem + 131072;              // 32768 B: [32 rows][1KB, swizzled]

    const int wg = blockIdx.x;
    const int xcd = wg & 7;
    const int slot = wg >> 3;            // 0..31
    const int g = slot & 1;              // b-group
    const int rem = slot >> 1;           // 0..15
    const int js = xcd * 4 + (rem & 3);  // 0..31 (XCD-contiguous j-slices)
    const int ks = rem >> 2;             // 0..3
    const int j0g = js * 64;
    const int b0 = g * 32;
    const int k0 = ks * 512;

    const int tid = threadIdx.x;
    const int lane = tid & 63;
    const int w = tid >> 6;              // 8 waves
    const int mi = w & 1;                // m-tile (16 b-rows)
    const int nt = w >> 1;               // n-tile (16 j-cols)

    // One-time weight fill: frag(gate, nt, u, lane) =
    //   W[j0g + nt*16 + (lane&15)][k0 + u*32 + (lane>>4)*8 ..+8]
    for (int q = 0; q < 16; ++q) {
        int e = q * 512 + tid;           // 0..8191
        int le = e & 63;
        int u = (e >> 6) & 15;
        int nte = (e >> 10) & 3;
        int gate = e >> 12;
        const _Float16* src = Wr + ((size_t)gate << 22) +
            (size_t)(j0g + nte * 16 + (le & 15)) * NH + k0 + u * 32 + (le >> 4) * 8;
        *(half8*)(Wlds + (((size_t)(gate * 4 + nte) * 16 + u) * 64 + le) * 8) =
            *(const half8*)src;
    }

    const int jj = j0g + nt * 16 + (lane & 15);  // this lane's j column
    const float bi_s = b_i[jj];
    const float bf_s = b_f[jj];

    // Owner state: h carry + first-step proj preload (plain loads: kernel
    // launch boundary made prior writes visible).
    float hprev[4], pc[4], pix[4], pfx[4];
    if (ks == 0) {
        const _Float16* hini = hslab + (size_t)(t0 & 3) * HSZ;
#pragma unroll
        for (int r = 0; r < 4; ++r) {
            int b = b0 + mi * 16 + (lane >> 4) * 4 + r;
            hprev[r] = (float)hini[(size_t)b * NH + jj];
            size_t pbase = (size_t)b * 6144 + jj;
            pc[r] = (float)proj[pbase];
            pix[r] = (float)proj[pbase + 2048];
            pfx[r] = (float)proj[pbase + 4096];
        }
    }

    __syncthreads();

    for (int s = 0; s < nsteps; ++s) {
        const int t = t0 + s;
        const _Float16* hin = hslab + (size_t)(t & 3) * HSZ;        // input t
        _Float16* hout = hslab + (size_t)((t + 1) & 3) * HSZ;       // output
        _Float16* hre = hslab + (size_t)((t + 3) & 3) * HSZ;        // re-arm

        // hstage WAR guard: all waves done reading hstage from step s-1.
        __syncthreads();

        // 1+2. poll OWN h chunks against canary (the poll IS the load), then
        //      stage into LDS (wave w: rows 4w..4w+3 x 512 k).
        {
            const _Float16* srcb = hin + (size_t)(b0 + w * 4) * NH + k0 + lane * 8;
            u32x4 q0, q1, q2, q3;
            while (true) {
                LLC_LD16NW(q0, srcb);
                LLC_LD16NW(q1, srcb + NH);
                LLC_LD16NW(q2, srcb + 2 * NH);
                LLC_LD16NW(q3, srcb + 3 * NH);
                wait_vm0();
                __builtin_amdgcn_sched_barrier(0);   // rule #18
                bool ok = no_canary16(q0) && no_canary16(q1) &&
                          no_canary16(q2) && no_canary16(q3);
                if (__all(ok)) break;
                __builtin_amdgcn_s_sleep(1);
            }
            __builtin_amdgcn_sched_barrier(0);
            const int r0 = w * 4;
            *(half8*)(hstage + (r0 + 0) * 1024 + ((lane * 16) ^ (((r0 + 0) & 7) << 4))) = __builtin_bit_cast(half8, q0);
            *(half8*)(hstage + (r0 + 1) * 1024 + ((lane * 16) ^ (((r0 + 1) & 7) << 4))) = __builtin_bit_cast(half8, q1);
            *(half8*)(hstage + (r0 + 2) * 1024 + ((lane * 16) ^ (((r0 + 2) & 7) << 4))) = __builtin_bit_cast(half8, q2);
            *(half8*)(hstage + (r0 + 3) * 1024 + ((lane * 16) ^ (((r0 + 3) & 7) << 4))) = __builtin_bit_cast(half8, q3);
        }
        __syncthreads();

        // 3. GEMM: wave (mi, nt): C[16x16] over K=512, both gates.
        f32x4 ci = {}, cf = {};
        {
            const int arow = mi * 16 + (lane & 15);
            const char* abase = hstage + arow * 1024;
            const int axor = (arow & 7) << 4;
            const _Float16* wbi = Wlds + (((size_t)(0 * 4 + nt) * 16) * 64 + lane) * 8;
            const _Float16* wbf = Wlds + (((size_t)(1 * 4 + nt) * 16) * 64 + lane) * 8;
#pragma unroll
            for (int u = 0; u < 16; ++u) {
                half8 a = *(const half8*)(abase + ((u * 64 + (lane >> 4) * 16) ^ axor));
                half8 wi = *(const half8*)(wbi + (size_t)u * 512);
                half8 wf = *(const half8*)(wbf + (size_t)u * 512);
                ci = __builtin_amdgcn_mfma_f32_16x16x32_f16(a, wi, ci, 0, 0, 0);
                cf = __builtin_amdgcn_mfma_f32_16x16x32_f16(a, wf, cf, 0, 0, 0);
            }
        }

        // part slot layout: [parity][g][js][kw(3)][wave(8)][lane*8 halves]
        const size_t tilebase = (size_t)(((t & 1) * 2 + g) * 32 + js) * 3;

        if (ks != 0) {
            // 4a. writer: pack 8 fp32 -> 8 fp16, ONE 16B store. Data IS flag.
            half8 pk;
#pragma unroll
            for (int r = 0; r < 4; ++r) {
                pk[r] = (_Float16)ci[r];
                pk[4 + r] = (_Float16)cf[r];
            }
            _Float16* pb = part + ((tilebase + (ks - 1)) * 8 + w) * 512 + lane * 8;
            LLC_ST16(pb, pk);
            // straight to next step: first to poll h_{t+1}.
        } else {
            // 4b. owner: poll the 3 packed slots; ALL 8 halves must be valid
            // (16B stores are only 64-bit atomic -- torn reads happen).
            _Float16* s0 = part + ((tilebase + 0) * 8 + w) * 512 + lane * 8;
            _Float16* s1 = part + ((tilebase + 1) * 8 + w) * 512 + lane * 8;
            _Float16* s2 = part + ((tilebase + 2) * 8 + w) * 512 + lane * 8;
            u32x4 q0, q1, q2;
            while (true) {
                LLC_LD16NW(q0, s0);
                LLC_LD16NW(q1, s1);
                LLC_LD16NW(q2, s2);
                wait_vm0();
                __builtin_amdgcn_sched_barrier(0);   // rule #18
                bool ok = no_canary16(q0) && no_canary16(q1) && no_canary16(q2);
                if (__all(ok)) break;
                __builtin_amdgcn_s_sleep(1);
            }
            __builtin_amdgcn_sched_barrier(0);

            // Re-arm canaries: partial slots (rewritten at t+2, same parity)
            // + this WG's h columns in slot (t+3)&3 (rewritten by THIS WG at
            // t+2). Both drained by the single vmcnt(0) below, BEFORE the h
            // publish -- so any consumer observing h_t implies re-arms landed.
            u32x4 can;
            can[0] = CANARY32; can[1] = CANARY32; can[2] = CANARY32; can[3] = CANARY32;
            LLC_ST16(s0, can);
            LLC_ST16(s1, can);
            LLC_ST16(s2, can);
            const unsigned can16 = CANARY16;
#pragma unroll
            for (int r = 0; r < 4; ++r) {
                int b = b0 + mi * 16 + (lane >> 4) * 4 + r;
                LLC_ST2(hre + (size_t)b * NH + jj, can16);
            }

            half8 p0 = __builtin_bit_cast(half8, q0);
            half8 p1 = __builtin_bit_cast(half8, q1);
            half8 p2 = __builtin_bit_cast(half8, q2);
#pragma unroll
            for (int r = 0; r < 4; ++r) {
                ci[r] += (float)p0[r] + (float)p1[r] + (float)p2[r];
                cf[r] += (float)p0[4 + r] + (float)p1[4 + r] + (float)p2[4 + r];
            }

            // Epilogue in VALU (hides the re-arm drain latency).
            float hn_keep[4];
            _Float16 hn16[4];
#pragma unroll
            for (int r = 0; r < 4; ++r) {
                float iv = 1.0f / (1.0f + __expf(-(ci[r] + pix[r] + bi_s)));
                float fv = 1.0f / (1.0f + __expf(-(cf[r] + pfx[r] + bf_s)));
                float z = iv * pc[r] + fv * hprev[r];
                float hn = 1.0f - 2.0f / (__expf(2.0f * z) + 1.0f);   // tanh(z)
                hprev[r] = hn;
                hn_keep[r] = hn;
                hn16[r] = (_Float16)hn;
            }

            wait_vm0();   // drain re-arms BEFORE publishing h (ordering proof)

            // Publish h_t: no drain, no barrier, no flag -- data IS the flag.
#pragma unroll
            for (int r = 0; r < 4; ++r) {
                int b = b0 + mi * 16 + (lane >> 4) * 4 + r;
                LLC_ST2(hout + (size_t)b * NH + jj, hn16[r]);
            }

            // Off-critical-path: out stores + proj prefetch for next step.
#pragma unroll
            for (int r = 0; r < 4; ++r) {
                int b = b0 + mi * 16 + (lane >> 4) * 4 + r;
                out[(size_t)t * (BATCH * NH) + (size_t)b * NH + jj] = hn_keep[r];
                if (t == T_SEQ - 1)
                    out[(size_t)T_SEQ * (BATCH * NH) + (size_t)b * NH + jj] = hn_keep[r];
            }
            if (s + 1 < nsteps) {
#pragma unroll
                for (int r = 0; r < 4; ++r) {
                    int b = b0 + mi * 16 + (lane >> 4) * 4 + r;
                    size_t pbase = ((size_t)(s + 1) * 64 + b) * 6144 + jj;
                    pc[r] = (float)proj[pbase];
                    pix[r] = (float)proj[pbase + 2048];
                    pfx[r] = (float)proj[pbase + 4096];
                }
            }
        }
    }
}

// ---------------- host launch -----------------------------------------------
extern "C" void kernel_launch(void* const* d_in, const int* in_sizes, int n_in,
                              void* d_out, int out_size, void* d_ws, size_t ws_size,
                              hipStream_t stream) {
    const float* x = (const float*)d_in[0];
    const float* hidden = (const float*)d_in[1];
    const float* W_cx = (const float*)d_in[2];
    const float* W_ih = (const float*)d_in[3];
    const float* W_ix = (const float*)d_in[4];
    const float* W_fh = (const float*)d_in[5];
    const float* W_fx = (const float*)d_in[6];
    const float* b_i = (const float*)d_in[7];
    const float* b_f = (const float*)d_in[8];
    float* out = (float*)d_out;

    char* ws = (char*)d_ws;
    size_t off = 0;
    auto alloc = [&](size_t bytes) {
        char* p = ws + off;
        off += (bytes + 255) & ~(size_t)255;
        return p;
    };
    _Float16* Wp = (_Float16*)alloc((size_t)6144 * NH * 2);       // 24 MB
    _Float16* Wr = (_Float16*)alloc((size_t)2 * NH * NH * 2);     // 16 MB
    _Float16* hslab = (_Float16*)alloc((size_t)4 * HSZ * 2);      // 1 MB
    const size_t part_bytes = (size_t)2 * 2 * 32 * 3 * 8 * 512 * 2;  // 3 MB
    _Float16* part = (_Float16*)alloc(part_bytes);
    const size_t fixed = off;

    int chunk = 32;
    for (int c = T_SEQ; c >= 32; c >>= 1) {
        size_t need = fixed + (size_t)c * 64 * NH * 2 + (size_t)c * 64 * 6144 * 2 + 1024;
        if (need <= ws_size) { chunk = c; break; }
    }
    _Float16* xh = (_Float16*)alloc((size_t)chunk * 64 * NH * 2);
    _Float16* proj = (_Float16*)alloc((size_t)chunk * 64 * 6144 * 2);

    // Arm canaries (in-graph, so every replay resets protocol state):
    // h slots 1..3 = canary; slot 0 gets hidden below. All partial slots.
    hipMemsetAsync(hslab + HSZ, 0xFF, (size_t)3 * HSZ * 2, stream);
    hipMemsetAsync(part, 0xFF, part_bytes, stream);

    const long long wsz = (long long)NH * NH;
    cvt_f32_f16<<<2048, 256, 0, stream>>>(W_cx, Wp, wsz);
    cvt_f32_f16<<<2048, 256, 0, stream>>>(W_ix, Wp + wsz, wsz);
    cvt_f32_f16<<<2048, 256, 0, stream>>>(W_fx, Wp + 2 * wsz, wsz);
    cvt_f32_f16<<<2048, 256, 0, stream>>>(W_ih, Wr, wsz);
    cvt_f32_f16<<<2048, 256, 0, stream>>>(W_fh, Wr + wsz, wsz);
    cvt_f32_f16<<<128, 256, 0, stream>>>(hidden, hslab, (long long)BATCH * NH);

    const int nch = T_SEQ / chunk;
    for (int c = 0; c < nch; ++c) {
        const int t0 = c * chunk;
        const int M = chunk * 64;
        cvt_f32_f16<<<2048, 256, 0, stream>>>(x + (size_t)t0 * 64 * NH, xh, (long long)M * NH);
        proj_gemm<<<dim3((M / 128) * 48), 256, 0, stream>>>(xh, Wp, proj, M);
        scan_kernel<<<256, 512, 163840, stream>>>(proj, Wr, hslab, b_i, b_f,
                                                  out, part, t0, chunk);
    }
}

// Round 11
// 9758.369 us; speedup vs baseline: 1.2412x; 1.2412x over previous
//
#include <hip/hip_runtime.h>
#include <cstdint>
#include <cstddef>

#define T_SEQ 1024
#define BATCH 64
#define NH 2048
// NINP == 2048 as well

typedef _Float16 half8 __attribute__((ext_vector_type(8)));
typedef _Float16 half4 __attribute__((ext_vector_type(4)));
typedef float f32x4 __attribute__((ext_vector_type(4)));
typedef unsigned u32x2 __attribute__((ext_vector_type(2)));

__device__ inline void gload_lds16(const void* g, void* l) {
    __builtin_amdgcn_global_load_lds(
        (const __attribute__((address_space(1))) uint32_t*)g,
        (__attribute__((address_space(3))) uint32_t*)l,
        16, 0, 0);
}

// LLC-bypass 16B load with compile-time byte offset (sc0 sc1: skip L1+L2,
// read at the coherence point = Infinity Cache).
#define LLC_LD16(dst, base, OFFSTR)                                         \
    asm volatile("global_load_dwordx4 %0, %1, off offset:" OFFSTR " sc0 sc1" \
                 : "=v"(dst) : "v"(base))

// LLC-bypass 2B store (write-through to the coherence point).
#define LLC_ST2(addr, val)                                                   \
    asm volatile("global_store_short %0, %1, off sc0 sc1"                    \
                 :: "v"(addr), "v"(val) : "memory")

// LLC-bypass 4B store / 8B load for the flag barrier.
#define LLC_ST4(addr, val)                                                   \
    asm volatile("global_store_dword %0, %1, off sc0 sc1"                    \
                 :: "v"(addr), "v"(val) : "memory")
#define LLC_LD8(dst, addr)                                                   \
    asm volatile("global_load_dwordx2 %0, %1, off sc0 sc1\n\ts_waitcnt vmcnt(0)" \
                 : "=v"(dst) : "v"(addr))

// Explicit drain: inline-asm VMEM stores are INVISIBLE to hipcc's waitcnt
// insertion, so s_barrier is NOT guaranteed to be preceded by vmcnt(0)
// (r5/r9 lesson: these races fire intermittently on graph replay).
__device__ inline void wait_vm0() {
    asm volatile("s_waitcnt vmcnt(0)" ::: "memory");
}

// ---------------- fp32 -> fp16 conversion (vectorized, n % 4 == 0) ----------
__global__ __launch_bounds__(256) void cvt_f32_f16(const float* __restrict__ src,
                                                   _Float16* __restrict__ dst,
                                                   long long n) {
    long long i = ((long long)blockIdx.x * 256 + threadIdx.x) * 4;
    long long stride = (long long)gridDim.x * 256 * 4;
    for (; i < n; i += stride) {
        const float4 v = *(const float4*)(src + i);
        half4 o;
        o[0] = (_Float16)v.x; o[1] = (_Float16)v.y;
        o[2] = (_Float16)v.z; o[3] = (_Float16)v.w;
        *(half4*)(dst + i) = o;
    }
}

// ---------------- projection GEMM: C[m][n] = sum_k A[m][k] * B[n][k] --------
// A: [M][2048] fp16, B: [6144][2048] fp16 (Wcx|Wix|Wfx rows), C: [M][6144] fp16
// Supertiled walk: 4 bm-rows per group, bn-major inside -> the 2MB A-panel
// stays L2-resident while B streams; B is re-read nbm/4 times (3.3GB) instead
// of nbm times (12GB). (proj was MALL-BW-bound, not MFMA-bound.)
__global__ __launch_bounds__(256) void proj_gemm(const _Float16* __restrict__ A,
                                                 const _Float16* __restrict__ B,
                                                 _Float16* __restrict__ C, int M) {
    __shared__ _Float16 As[128][64];
    __shared__ _Float16 Bs[128][64];
    const int NBN = 48;                 // 6144 / 128
    const int GH = 4;                   // bm-rows per supertile group (nbm%4==0)
    const int nbm = M >> 7;
    const int nwg = nbm * NBN;          // divisible by 8 (M >= 2048)
    const int per = nwg >> 3;
    const int bid = blockIdx.x;
    const int swz = (bid & 7) * per + (bid >> 3);   // XCD-aware swizzle (bijective)
    const int group = swz / (GH * NBN);
    const int rem = swz % (GH * NBN);
    const int bm = group * GH + (rem & (GH - 1));
    const int bn = rem / GH;

    const int tid = threadIdx.x;
    const int lane = tid & 63, w = tid >> 6;
    const int wm = w & 1, wn = w >> 1;

    f32x4 acc[4][4] = {};

    const int srow = lane >> 3;         // 0..7
    const int scol = (lane & 7) * 8;    // half units

    for (int bk = 0; bk < NH / 64; ++bk) {
#pragma unroll
        for (int i = 0; i < 4; ++i) {
            int r = w * 32 + i * 8;
            const _Float16* gA = A + (size_t)(bm * 128 + r + srow) * NH + bk * 64 + scol;
            gload_lds16(gA, &As[r][0]);
            const _Float16* gB = B + (size_t)(bn * 128 + r + srow) * NH + bk * 64 + scol;
            gload_lds16(gB, &Bs[r][0]);
        }
        __syncthreads();
#pragma unroll
        for (int kk = 0; kk < 2; ++kk) {
            half8 af[4], bf[4];
#pragma unroll
            for (int mi = 0; mi < 4; ++mi)
                af[mi] = *(const half8*)&As[wm * 64 + mi * 16 + (lane & 15)][kk * 32 + (lane >> 4) * 8];
#pragma unroll
            for (int ni = 0; ni < 4; ++ni)
                bf[ni] = *(const half8*)&Bs[wn * 64 + ni * 16 + (lane & 15)][kk * 32 + (lane >> 4) * 8];
#pragma unroll
            for (int mi = 0; mi < 4; ++mi)
#pragma unroll
                for (int ni = 0; ni < 4; ++ni)
                    acc[mi][ni] = __builtin_amdgcn_mfma_f32_16x16x32_f16(af[mi], bf[ni], acc[mi][ni], 0, 0, 0);
        }
        __syncthreads();
    }
#pragma unroll
    for (int mi = 0; mi < 4; ++mi)
#pragma unroll
        for (int ni = 0; ni < 4; ++ni)
#pragma unroll
            for (int r = 0; r < 4; ++r) {
                int m = bm * 128 + wm * 64 + mi * 16 + (lane >> 4) * 4 + r;
                int n = bn * 128 + wn * 64 + ni * 16 + (lane & 15);
                C[(size_t)m * 6144 + n] = (_Float16)acc[mi][ni][r];
            }
}

// ---------------- persistent scan kernel (r3 champion + fixes) --------------
// 256 WGs x 512 threads, 1 WG/CU. Each WG: b-group g (32 rows), j-slice of 16
// cols (XCD-contiguous), FULL k (one-hop design -- best measured). Weights
// (128KB) in LDS in MFMA B-fragment order. Cross-step h via LLC bypass.
// Barrier: per-WG flag stores + wave-0 polls its group's 128 flags.
// Fixes vs r3: conflict-free red[] layout (37.7M conflicts -> 0); explicit
// vmcnt(0) drain of asm h-stores before the arrive barrier (r5/r9 race class).
__global__ __launch_bounds__(512, 1) void scan_kernel(
    const _Float16* __restrict__ proj,   // [nsteps*64][6144] fp16 (c | ix | fx)
    const _Float16* __restrict__ Wr,     // [2][2048][2048] fp16 (W_ih, W_fh)
    _Float16* hb0, _Float16* hb1,        // [64][2048] fp16 ping-pong
    const float* __restrict__ b_i, const float* __restrict__ b_f,
    float* __restrict__ out,             // d_out: [1024][64][2048] + [64][2048]
    unsigned* flags, int t0, int nsteps) {
    extern __shared__ char smem[];
    _Float16* Wlds = (_Float16*)smem;          // 131072 B
    float* red = (float*)(smem + 131072);      // 12288 B: [6 slots][8 regs][64 lanes]

    const int wg = blockIdx.x;
    const int xcd = wg & 7;
    const int slot = wg >> 3;            // 0..31
    const int g = slot & 1;              // b-group
    const int idx = xcd * 16 + (slot >> 1);   // 0..127, contiguous per XCD
    const int j0 = idx * 16;
    const int b0 = g * 32;
    unsigned* flags_g = flags + g * 256;      // 1KB apart per group

    const int tid = threadIdx.x;
    const int lane = tid & 63;
    const int w = tid >> 6;      // 8 waves
    const int mi = w & 1;        // m-tile (16 rows)
    const int kq = w >> 1;       // k-quarter (512 k)

    // One-time fill of LDS weight fragments:
    // fragment (gate, kk 0..63, lane l) = W[j0 + (l&15)][kk*32 + (l>>4)*8 .. +8]
    for (int q = 0; q < 16; ++q) {
        int e = q * 512 + tid;            // 0..8191
        int l = e & 63;
        int fk = (e >> 6) & 63;
        int gate = e >> 12;
        const _Float16* src = Wr + ((size_t)gate << 22) +
                              (size_t)(j0 + (l & 15)) * NH + fk * 32 + (l >> 4) * 8;
        *(half8*)(Wlds + ((size_t)(gate * 64 + fk) * 64 + l) * 8) = *(const half8*)src;
    }

    const float bi_s = b_i[j0 + (lane & 15)];
    const float bf_s = b_f[j0 + (lane & 15)];

    // h[b][j] carry + first-step proj preload (epilogue waves only).
    float hprev[4], pc[4], pix[4], pfx[4];
    if (kq == 0) {
        const _Float16* hini = (t0 & 1) ? hb1 : hb0;
#pragma unroll
        for (int r = 0; r < 4; ++r) {
            int b = b0 + mi * 16 + (lane >> 4) * 4 + r;
            int j = j0 + (lane & 15);
            unsigned tmp;
            asm volatile("global_load_ushort %0, %1, off sc0 sc1\n\ts_waitcnt vmcnt(0)"
                         : "=v"(tmp) : "v"(hini + (size_t)b * NH + j));
            hprev[r] = (float)__builtin_bit_cast(_Float16, (unsigned short)tmp);
            size_t pbase = ((size_t)b) * 6144 + j;
            pc[r] = (float)proj[pbase];
            pix[r] = (float)proj[pbase + 2048];
            pfx[r] = (float)proj[pbase + 4096];
        }
    }

    __syncthreads();

    for (int s = 0; s < nsteps; ++s) {
        const int t = t0 + s;
        const _Float16* hcur = (t & 1) ? hb1 : hb0;
        _Float16* hnxt = (t & 1) ? hb0 : hb1;

        // A fragments: this wave's 16 rows x 512-k quarter. LLC-bypass loads,
        // issued as one batch, one vmcnt(0) wait (~1 LLC latency).
        half8 afr[16];
        const _Float16* hrow = hcur + (size_t)(b0 + mi * 16 + (lane & 15)) * NH +
                               kq * 512 + (lane >> 4) * 8;
        LLC_LD16(afr[0],  hrow, "0");
        LLC_LD16(afr[1],  hrow, "64");
        LLC_LD16(afr[2],  hrow, "128");
        LLC_LD16(afr[3],  hrow, "192");
        LLC_LD16(afr[4],  hrow, "256");
        LLC_LD16(afr[5],  hrow, "320");
        LLC_LD16(afr[6],  hrow, "384");
        LLC_LD16(afr[7],  hrow, "448");
        LLC_LD16(afr[8],  hrow, "512");
        LLC_LD16(afr[9],  hrow, "576");
        LLC_LD16(afr[10], hrow, "640");
        LLC_LD16(afr[11], hrow, "704");
        LLC_LD16(afr[12], hrow, "768");
        LLC_LD16(afr[13], hrow, "832");
        LLC_LD16(afr[14], hrow, "896");
        LLC_LD16(afr[15], hrow, "960");
        wait_vm0();
        __builtin_amdgcn_sched_barrier(0);   // rule #18: keep MFMA below the wait

        f32x4 ai0 = {}, ai1 = {}, af0 = {}, af1 = {};
#pragma unroll
        for (int u = 0; u < 16; ++u) {
            int fk = kq * 16 + u;
            half8 wi = *(const half8*)(Wlds + ((size_t)fk * 64 + lane) * 8);
            half8 wf = *(const half8*)(Wlds + ((size_t)(64 + fk) * 64 + lane) * 8);
            if (u & 1) {
                ai1 = __builtin_amdgcn_mfma_f32_16x16x32_f16(afr[u], wi, ai1, 0, 0, 0);
                af1 = __builtin_amdgcn_mfma_f32_16x16x32_f16(afr[u], wf, af1, 0, 0, 0);
            } else {
                ai0 = __builtin_amdgcn_mfma_f32_16x16x32_f16(afr[u], wi, ai0, 0, 0, 0);
                af0 = __builtin_amdgcn_mfma_f32_16x16x32_f16(afr[u], wf, af0, 0, 0, 0);
            }
        }
        f32x4 acc_i = ai0 + ai1;
        f32x4 acc_f = af0 + af1;

        // k-reduce staging: [slot][reg][lane] layout, lane stride 4B -> no
        // bank conflicts (r3's f32x4-strided layout was 16-way, 37.7M/disp).
        if (kq != 0) {
            const int sl = mi * 3 + (kq - 1);
#pragma unroll
            for (int r = 0; r < 4; ++r) {
                red[(sl * 8 + r) * 64 + lane] = acc_i[r];
                red[(sl * 8 + 4 + r) * 64 + lane] = acc_f[r];
            }
        }
        __syncthreads();

        float hn_keep[4];
        if (kq == 0) {
#pragma unroll
            for (int p = 0; p < 3; ++p) {
                const int sl = mi * 3 + p;
#pragma unroll
                for (int r = 0; r < 4; ++r) {
                    acc_i[r] += red[(sl * 8 + r) * 64 + lane];
                    acc_f[r] += red[(sl * 8 + 4 + r) * 64 + lane];
                }
            }
#pragma unroll
            for (int r = 0; r < 4; ++r) {
                int b = b0 + mi * 16 + (lane >> 4) * 4 + r;
                int j = j0 + (lane & 15);
                float iv = 1.0f / (1.0f + __expf(-(acc_i[r] + pix[r] + bi_s)));
                float fv = 1.0f / (1.0f + __expf(-(acc_f[r] + pfx[r] + bf_s)));
                float z = iv * pc[r] + fv * hprev[r];
                float hn = 1.0f - 2.0f / (__expf(2.0f * z) + 1.0f);   // tanh(z)
                hprev[r] = hn;
                hn_keep[r] = hn;
                _Float16 hn16 = (_Float16)hn;
                LLC_ST2(hnxt + (size_t)b * NH + j, hn16);             // -> LLC
            }
            wait_vm0();   // asm h-stores are invisible to hipcc: drain before
        }                 // the barrier so the flag can't outrun them (r5/r9)
        __syncthreads();

        const unsigned tv = (unsigned)(t + 1);
        // Arrive: one flag STORE per WG (distinct addresses -> no RMW serial).
        if (tid == 0) {
            unsigned* myflag = flags_g + idx;
            LLC_ST4(myflag, tv);
        }
        // out-stores: issued after arrive; they complete during the poll.
        if (kq == 0) {
#pragma unroll
            for (int r = 0; r < 4; ++r) {
                int b = b0 + mi * 16 + (lane >> 4) * 4 + r;
                int j = j0 + (lane & 15);
                out[(size_t)t * (BATCH * NH) + (size_t)b * NH + j] = hn_keep[r];
                if (t == T_SEQ - 1)
                    out[(size_t)T_SEQ * (BATCH * NH) + (size_t)b * NH + j] = hn_keep[r];
            }
            // proj prefetch for next step (consumed after the barrier).
            if (s + 1 < nsteps) {
#pragma unroll
                for (int r = 0; r < 4; ++r) {
                    int b = b0 + mi * 16 + (lane >> 4) * 4 + r;
                    int j = j0 + (lane & 15);
                    size_t pbase = ((size_t)(s + 1) * 64 + b) * 6144 + j;
                    pc[r] = (float)proj[pbase];
                    pix[r] = (float)proj[pbase + 2048];
                    pfx[r] = (float)proj[pbase + 4096];
                }
            }
        }
        // Wave 0 polls all 128 flags of its group (4 cache lines, 2 per lane).
        if (w == 0) {
            const unsigned* fb = flags_g + lane * 2;
            while (true) {
                u32x2 v;
                LLC_LD8(v, fb);
                if (__all(v[0] >= tv && v[1] >= tv)) break;
                __builtin_amdgcn_s_sleep(1);
            }
        }
        __syncthreads();
    }
}

// ---------------- host launch -----------------------------------------------
extern "C" void kernel_launch(void* const* d_in, const int* in_sizes, int n_in,
                              void* d_out, int out_size, void* d_ws, size_t ws_size,
                              hipStream_t stream) {
    const float* x = (const float*)d_in[0];
    const float* hidden = (const float*)d_in[1];
    const float* W_cx = (const float*)d_in[2];
    const float* W_ih = (const float*)d_in[3];
    const float* W_ix = (const float*)d_in[4];
    const float* W_fh = (const float*)d_in[5];
    const float* W_fx = (const float*)d_in[6];
    const float* b_i = (const float*)d_in[7];
    const float* b_f = (const float*)d_in[8];
    float* out = (float*)d_out;

    char* ws = (char*)d_ws;
    size_t off = 0;
    auto alloc = [&](size_t bytes) {
        char* p = ws + off;
        off += (bytes + 255) & ~(size_t)255;
        return p;
    };
    _Float16* Wp = (_Float16*)alloc((size_t)6144 * NH * 2);       // 24 MB
    _Float16* Wr = (_Float16*)alloc((size_t)2 * NH * NH * 2);     // 16 MB
    _Float16* hb0 = (_Float16*)alloc((size_t)BATCH * NH * 2);
    _Float16* hb1 = (_Float16*)alloc((size_t)BATCH * NH * 2);
    unsigned* flags = (unsigned*)alloc(4096);
    const size_t fixed = off;

    int chunk = 32;
    for (int c = T_SEQ; c >= 32; c >>= 1) {
        size_t need = fixed + (size_t)c * 64 * NH * 2 + (size_t)c * 64 * 6144 * 2 + 1024;
        if (need <= ws_size) { chunk = c; break; }
    }
    _Float16* xh = (_Float16*)alloc((size_t)chunk * 64 * NH * 2);
    _Float16* proj = (_Float16*)alloc((size_t)chunk * 64 * 6144 * 2);

    hipMemsetAsync(flags, 0, 4096, stream);

    const long long wsz = (long long)NH * NH;
    cvt_f32_f16<<<2048, 256, 0, stream>>>(W_cx, Wp, wsz);
    cvt_f32_f16<<<2048, 256, 0, stream>>>(W_ix, Wp + wsz, wsz);
    cvt_f32_f16<<<2048, 256, 0, stream>>>(W_fx, Wp + 2 * wsz, wsz);
    cvt_f32_f16<<<2048, 256, 0, stream>>>(W_ih, Wr, wsz);
    cvt_f32_f16<<<2048, 256, 0, stream>>>(W_fh, Wr + wsz, wsz);
    cvt_f32_f16<<<128, 256, 0, stream>>>(hidden, hb0, (long long)BATCH * NH);

    const int nch = T_SEQ / chunk;
    for (int c = 0; c < nch; ++c) {
        const int t0 = c * chunk;
        const int M = chunk * 64;
        cvt_f32_f16<<<2048, 256, 0, stream>>>(x + (size_t)t0 * 64 * NH, xh, (long long)M * NH);
        proj_gemm<<<dim3((M / 128) * 48), 256, 0, stream>>>(xh, Wp, proj, M);
        scan_kernel<<<256, 512, 143360, stream>>>(proj, Wr, hb0, hb1, b_i, b_f,
                                                  out, flags, t0, chunk);
    }
}